// Round 1
// baseline (841.820 us; speedup 1.0000x reference)
//
#include <hip/hip_runtime.h>

#define HN 8
#define PP 4
#define DH 32
#define NQc 8192
#define NBc 8
#define NVc 16384
#define EE 256
#define HWc 128

// ---------------- pack [W_off | W_attn | 0] into 256x128 + bias 128 ----------------
__global__ void build_wcat(const float* __restrict__ Woff, const float* __restrict__ boff,
                           const float* __restrict__ Wattn, const float* __restrict__ battn,
                           float* __restrict__ Wcat, float* __restrict__ bcat) {
  int idx = blockIdx.x * 256 + threadIdx.x;
  if (idx < 256 * 128) {
    int k = idx >> 7, c = idx & 127;
    float v = 0.f;
    if (c < 64) v = Woff[k * 64 + c];
    else if (c < 96) v = Wattn[k * 32 + (c - 64)];
    Wcat[idx] = v;
  } else if (idx < 256 * 128 + 128) {
    int c = idx - 256 * 128;
    float v = 0.f;
    if (c < 64) v = boff[c];
    else if (c < 96) v = battn[c - 64];
    bcat[c] = v;
  }
}

// ---------------- tiled f32 GEMM: C(Mx ldw) = A(Mx256) @ W(256 x ldw) + bias ----------------
// BM=BN=128, BK=16, 256 threads, 8x8 per-thread microtile in 2x2 quadrants of 4x4.
#define MODE_VAL 0    // permuted store to (B,HN,NV,DH)
#define MODE_PLAIN 1  // plain store, stride ldw
#define MODE_OUT 2    // + bias + residual, stride 256

template <int MODE>
__global__ __launch_bounds__(256) void gemm128(
    const float* __restrict__ A, const float* __restrict__ Wm,
    const float* __restrict__ bias, const float* __restrict__ resid,
    float* __restrict__ out, int ldw) {
  __shared__ float As[16][128];
  __shared__ float Ws[16][128];
  const int t = threadIdx.x;
  const int bm = blockIdx.x * 128;
  const int bn = blockIdx.y * 128;
  const int tx4 = (t & 15) * 4;
  const int ty4 = (t >> 4) * 4;
  const int lr = t >> 2;            // 0..63  (A-load row)
  const int lk = (t & 3) * 4;       // A-load k offset
  const int wk = t >> 5;            // 0..7   (W-load k row)
  const int wn = (t & 31) * 4;      // W-load col offset

  float acc[8][8];
#pragma unroll
  for (int i = 0; i < 8; ++i)
#pragma unroll
    for (int j = 0; j < 8; ++j) acc[i][j] = 0.f;

  for (int k0 = 0; k0 < 256; k0 += 16) {
    float4 a0 = *(const float4*)(A + (size_t)(bm + lr) * 256 + k0 + lk);
    float4 a1 = *(const float4*)(A + (size_t)(bm + lr + 64) * 256 + k0 + lk);
    float4 w0 = *(const float4*)(Wm + (size_t)(k0 + wk) * ldw + bn + wn);
    float4 w1 = *(const float4*)(Wm + (size_t)(k0 + wk + 8) * ldw + bn + wn);
    __syncthreads();
    As[lk + 0][lr] = a0.x; As[lk + 1][lr] = a0.y; As[lk + 2][lr] = a0.z; As[lk + 3][lr] = a0.w;
    As[lk + 0][lr + 64] = a1.x; As[lk + 1][lr + 64] = a1.y; As[lk + 2][lr + 64] = a1.z; As[lk + 3][lr + 64] = a1.w;
    *(float4*)&Ws[wk][wn] = w0;
    *(float4*)&Ws[wk + 8][wn] = w1;
    __syncthreads();
#pragma unroll
    for (int kk = 0; kk < 16; ++kk) {
      float4 av0 = *(const float4*)&As[kk][ty4];
      float4 av1 = *(const float4*)&As[kk][ty4 + 64];
      float4 bv0 = *(const float4*)&Ws[kk][tx4];
      float4 bv1 = *(const float4*)&Ws[kk][tx4 + 64];
      float am[8] = {av0.x, av0.y, av0.z, av0.w, av1.x, av1.y, av1.z, av1.w};
      float bb[8] = {bv0.x, bv0.y, bv0.z, bv0.w, bv1.x, bv1.y, bv1.z, bv1.w};
#pragma unroll
      for (int i = 0; i < 8; ++i)
#pragma unroll
        for (int j = 0; j < 8; ++j) acc[i][j] += am[i] * bb[j];
    }
  }

#pragma unroll
  for (int i = 0; i < 8; ++i) {
    const int row = bm + ty4 + (i & 3) + (i >> 2) * 64;
#pragma unroll
    for (int jq = 0; jq < 2; ++jq) {
      const int col0 = bn + tx4 + jq * 64;
      float4 r;
      r.x = acc[i][jq * 4 + 0] + bias[col0 + 0];
      r.y = acc[i][jq * 4 + 1] + bias[col0 + 1];
      r.z = acc[i][jq * 4 + 2] + bias[col0 + 2];
      r.w = acc[i][jq * 4 + 3] + bias[col0 + 3];
      if (MODE == MODE_VAL) {
        // row -> (b, n), col -> (h, d); store v_t layout (B,HN,NV,DH)
        const int b = row >> 14, n = row & (NVc - 1);
        const int h = col0 >> 5, d0 = col0 & 31;
        float* o = out + (((size_t)(b * HN + h) * NVc + n) * DH + d0);
        *(float4*)o = r;
      } else if (MODE == MODE_PLAIN) {
        *(float4*)(out + (size_t)row * ldw + col0) = r;
      } else {
        const size_t off = (size_t)row * 256 + col0;
        float4 rs = *(const float4*)(resid + off);
        r.x += rs.x; r.y += rs.y; r.z += rs.z; r.w += rs.w;
        *(float4*)(out + off) = r;
      }
    }
  }
}

// ---------------- bilinear sampling + softmax-weighted accumulation ----------------
// block: one (b,h) slice x 8 queries x 32 dh.  grid.x = 64 * 1024
__global__ __launch_bounds__(256) void sample_kernel(
    const float* __restrict__ vbuf,   // (B,HN,NV,DH)
    const float* __restrict__ oa,     // (B*NQ, 128): [0,64) off, [64,96) logits
    const float* __restrict__ ref2d,  // (B,NQ,2)
    float* __restrict__ outs) {       // (B*NQ, 256), col = h*32+d
  const int t = threadIdx.x;
  const int d = t & 31;
  const int ql = t >> 5;              // 0..7
  const int sl = blockIdx.x >> 10;    // 0..63 = b*8+h
  const int qc = blockIdx.x & 1023;
  const int b = sl >> 3;
  const int h = sl & 7;
  const int q = qc * 8 + ql;
  const size_t bq = (size_t)b * NQc + q;
  const float* oarow = oa + bq * 128;
  const float rx = ref2d[bq * 2 + 0];
  const float ry = ref2d[bq * 2 + 1];

  const float l0 = oarow[64 + h * 4 + 0];
  const float l1 = oarow[64 + h * 4 + 1];
  const float l2 = oarow[64 + h * 4 + 2];
  const float l3 = oarow[64 + h * 4 + 3];
  const float mx = fmaxf(fmaxf(l0, l1), fmaxf(l2, l3));
  float ee[4];
  ee[0] = expf(l0 - mx); ee[1] = expf(l1 - mx); ee[2] = expf(l2 - mx); ee[3] = expf(l3 - mx);
  const float inv = 1.0f / (ee[0] + ee[1] + ee[2] + ee[3]);

  const float* vb = vbuf + (size_t)sl * NVc * DH + d;
  float acc = 0.f;
#pragma unroll
  for (int p = 0; p < PP; ++p) {
    const float ox = oarow[h * 8 + p * 2 + 0];
    const float oy = oarow[h * 8 + p * 2 + 1];
    const float x = (rx + ox * (1.0f / HWc)) * (float)HWc - 0.5f;
    const float y = (ry + oy * (1.0f / HWc)) * (float)HWc - 0.5f;
    const float x0f = floorf(x), y0f = floorf(y);
    const int x0 = (int)x0f, y0 = (int)y0f;
    const int x1 = x0 + 1, y1 = y0 + 1;
    const float wx1 = x - x0f, wx0 = 1.f - wx1;
    const float wy1 = y - y0f, wy0 = 1.f - wy1;
    const bool vx0 = (unsigned)x0 < HWc, vx1 = (unsigned)x1 < HWc;
    float s = 0.f;
    if ((unsigned)y0 < HWc) {
      const float* r = vb + (size_t)y0 * (HWc * DH);
      if (vx0) s += wx0 * wy0 * r[x0 * DH];
      if (vx1) s += wx1 * wy0 * r[x1 * DH];
    }
    if ((unsigned)y1 < HWc) {
      const float* r = vb + (size_t)y1 * (HWc * DH);
      if (vx0) s += wx0 * wy1 * r[x0 * DH];
      if (vx1) s += wx1 * wy1 * r[x1 * DH];
    }
    acc += ee[p] * inv * s;
  }
  outs[bq * EE + h * DH + d] = acc;
}

extern "C" void kernel_launch(void* const* d_in, const int* in_sizes, int n_in,
                              void* d_out, int out_size, void* d_ws, size_t ws_size,
                              hipStream_t stream) {
  const float* query = (const float*)d_in[0];
  const float* value = (const float*)d_in[1];
  const float* ref2d = (const float*)d_in[2];
  const float* Woff  = (const float*)d_in[4];
  const float* boff  = (const float*)d_in[5];
  const float* Wattn = (const float*)d_in[6];
  const float* battn = (const float*)d_in[7];
  const float* Wval  = (const float*)d_in[8];
  const float* bval  = (const float*)d_in[9];
  const float* Wout  = (const float*)d_in[10];
  const float* bout  = (const float*)d_in[11];
  float* out = (float*)d_out;
  float* ws = (float*)d_ws;

  float* vbuf  = ws;                      // 8*8*16384*32      = 33,554,432 f
  float* oabuf = vbuf + 33554432;         // 65536*128         =  8,388,608 f
  float* sbuf  = oabuf + 8388608;         // 65536*256         = 16,777,216 f
  float* Wcat  = sbuf + 16777216;         // 256*128
  float* bcat  = Wcat + 32768;            // 128

  build_wcat<<<129, 256, 0, stream>>>(Woff, boff, Wattn, battn, Wcat, bcat);

  dim3 gv(1024, 2);  // M = 131072, N = 256
  gemm128<MODE_VAL><<<gv, 256, 0, stream>>>(value, Wval, bval, nullptr, vbuf, 256);

  dim3 go(512, 1);   // M = 65536, N = 128 (padded 96)
  gemm128<MODE_PLAIN><<<go, 256, 0, stream>>>(query, Wcat, bcat, nullptr, oabuf, 128);

  sample_kernel<<<65536, 256, 0, stream>>>(vbuf, oabuf, ref2d, sbuf);

  dim3 gf(512, 2);   // M = 65536, N = 256
  gemm128<MODE_OUT><<<gf, 256, 0, stream>>>(sbuf, Wout, bout, query, out, 256);
}

// Round 2
// 508.337 us; speedup vs baseline: 1.6560x; 1.6560x over previous
//
#include <hip/hip_runtime.h>

typedef short s16x8 __attribute__((ext_vector_type(8)));
typedef float f32x4 __attribute__((ext_vector_type(4)));

#define HN 8
#define PP 4
#define DH 32
#define NQc 8192
#define NVc 16384
#define EE 256
#define HWc 128

__device__ __forceinline__ unsigned short f2bf(float x) {
  unsigned u = __float_as_uint(x);
  u += 0x7FFF + ((u >> 16) & 1);   // RNE
  return (unsigned short)(u >> 16);
}

// ---------- weight prep: transpose+convert to bf16 [N][K] layout, build bcat ----------
__global__ __launch_bounds__(256) void wprep(
    const float* __restrict__ Wval, const float* __restrict__ Wout,
    const float* __restrict__ Woff, const float* __restrict__ Wattn,
    const float* __restrict__ boff, const float* __restrict__ battn,
    unsigned short* __restrict__ wvt, unsigned short* __restrict__ wot,
    unsigned short* __restrict__ wct, float* __restrict__ bcat) {
  int g = blockIdx.x * 256 + threadIdx.x;
  if (g < 65536) {
    int n = g >> 8, k = g & 255;
    wvt[n * 256 + k] = f2bf(Wval[k * 256 + n]);
  } else if (g < 131072) {
    int g2 = g - 65536;
    int n = g2 >> 8, k = g2 & 255;
    wot[n * 256 + k] = f2bf(Wout[k * 256 + n]);
  } else if (g < 163840) {
    int g2 = g - 131072;
    int n = g2 >> 8, k = g2 & 255;
    float v = 0.f;
    if (n < 64) v = Woff[k * 64 + n];
    else if (n < 96) v = Wattn[k * 32 + (n - 64)];
    wct[n * 256 + k] = f2bf(v);
  } else if (g < 163968) {
    int c = g - 163840;
    bcat[c] = (c < 64) ? boff[c] : ((c < 96) ? battn[c - 64] : 0.f);
  }
}

// ---------- bf16 MFMA GEMM: C(M x N) = A(M x 256) @ Wt^T + bias ----------
// Wt is bf16 [N][256] (k-contiguous). BM=BN=128, BK=32, 256 thr = 4 waves,
// each wave a 64x64 quadrant as 4x4 tiles of mfma_f32_16x16x32_bf16.
#define MODE_VAL 0    // permuted store to (B,HN,NV,DH)
#define MODE_PLAIN 1  // plain store, stride ldw
#define MODE_OUT 2    // + residual, stride 256

template <int MODE, bool ABF16>
__global__ __launch_bounds__(256) void mfma_gemm(
    const void* __restrict__ Ain, const unsigned short* __restrict__ Wt,
    const float* __restrict__ bias, const float* __restrict__ resid,
    float* __restrict__ out, int ldw) {
  __shared__ unsigned short As[128 * 40];  // row stride 40 bf16 (80B) -> <=2-way banks
  __shared__ unsigned short Ws[128 * 40];
  const int t = threadIdx.x;
  const int lane = t & 63, wave = t >> 6;
  const int lane15 = lane & 15, quad = lane >> 4;
  const int wr = wave >> 1, wc = wave & 1;
  const int bm = blockIdx.x * 128, bn = blockIdx.y * 128;

  f32x4 acc[4][4];
#pragma unroll
  for (int i = 0; i < 4; ++i)
#pragma unroll
    for (int j = 0; j < 4; ++j)
#pragma unroll
      for (int r = 0; r < 4; ++r) acc[i][j][r] = 0.f;

  for (int k0 = 0; k0 < 256; k0 += 32) {
    float4 av[4];
    uint4 av2[2];
    uint4 wv[2];
    if (!ABF16) {
      const float* Af = (const float*)Ain;
#pragma unroll
      for (int i = 0; i < 4; ++i) {
        int row = i * 32 + (t >> 3);
        av[i] = *(const float4*)(Af + (size_t)(bm + row) * 256 + k0 + (t & 7) * 4);
      }
    } else {
      const unsigned short* Ab = (const unsigned short*)Ain;
#pragma unroll
      for (int i = 0; i < 2; ++i) {
        int s = i * 256 + t;
        av2[i] = *(const uint4*)(Ab + (size_t)(bm + (s >> 2)) * 256 + k0 + (s & 3) * 8);
      }
    }
#pragma unroll
    for (int i = 0; i < 2; ++i) {
      int s = i * 256 + t;
      wv[i] = *(const uint4*)(Wt + (size_t)(bn + (s >> 2)) * 256 + k0 + (s & 3) * 8);
    }
    __syncthreads();
    if (!ABF16) {
#pragma unroll
      for (int i = 0; i < 4; ++i) {
        int row = i * 32 + (t >> 3);
        ushort4 c;
        c.x = f2bf(av[i].x); c.y = f2bf(av[i].y); c.z = f2bf(av[i].z); c.w = f2bf(av[i].w);
        *(ushort4*)&As[row * 40 + (t & 7) * 4] = c;
      }
    } else {
#pragma unroll
      for (int i = 0; i < 2; ++i) {
        int s = i * 256 + t;
        *(uint4*)&As[(s >> 2) * 40 + (s & 3) * 8] = av2[i];
      }
    }
#pragma unroll
    for (int i = 0; i < 2; ++i) {
      int s = i * 256 + t;
      *(uint4*)&Ws[(s >> 2) * 40 + (s & 3) * 8] = wv[i];
    }
    __syncthreads();
    s16x8 af[4], bfr[4];
#pragma unroll
    for (int tm = 0; tm < 4; ++tm)
      af[tm] = *(const s16x8*)&As[(wr * 64 + tm * 16 + lane15) * 40 + quad * 8];
#pragma unroll
    for (int tn = 0; tn < 4; ++tn)
      bfr[tn] = *(const s16x8*)&Ws[(wc * 64 + tn * 16 + lane15) * 40 + quad * 8];
#pragma unroll
    for (int tm = 0; tm < 4; ++tm)
#pragma unroll
      for (int tn = 0; tn < 4; ++tn)
        acc[tm][tn] = __builtin_amdgcn_mfma_f32_16x16x32_bf16(af[tm], bfr[tn], acc[tm][tn], 0, 0, 0);
  }

#pragma unroll
  for (int tm = 0; tm < 4; ++tm) {
#pragma unroll
    for (int tn = 0; tn < 4; ++tn) {
      const int col = bn + wc * 64 + tn * 16 + lane15;
      const float bcol = bias[col];
#pragma unroll
      for (int r = 0; r < 4; ++r) {
        const int row = bm + wr * 64 + tm * 16 + quad * 4 + r;
        float v = acc[tm][tn][r] + bcol;
        if (MODE == MODE_VAL) {
          const int b = row >> 14, n = row & (NVc - 1);
          const int h = col >> 5, d = col & 31;
          out[(((size_t)(b * HN + h) * NVc + n) * DH) + d] = v;
        } else if (MODE == MODE_PLAIN) {
          out[(size_t)row * ldw + col] = v;
        } else {
          const size_t off = (size_t)row * 256 + col;
          out[off] = v + resid[off];
        }
      }
    }
  }
}

// ---------- precompute packed corner indices + masked attn-weighted bilinear weights ----------
// one thread per (b,q,h); meta block = 20 uints: [0..3] packed x0|y0|x1|y1 per p,
// [4..19] four float4 weights (w00,w10,w01,w11) premultiplied by softmax attn & validity.
__global__ __launch_bounds__(256) void prep_points(
    const float* __restrict__ oa, const float* __restrict__ ref2d,
    unsigned int* __restrict__ meta) {
  const int g = blockIdx.x * 256 + threadIdx.x;  // 0..524287
  const int bq = g >> 3, h = g & 7;
  const float* oarow = oa + (size_t)bq * 128;
  const float rx = ref2d[(size_t)bq * 2 + 0];
  const float ry = ref2d[(size_t)bq * 2 + 1];

  const float l0 = oarow[64 + h * 4 + 0];
  const float l1 = oarow[64 + h * 4 + 1];
  const float l2 = oarow[64 + h * 4 + 2];
  const float l3 = oarow[64 + h * 4 + 3];
  const float mx = fmaxf(fmaxf(l0, l1), fmaxf(l2, l3));
  float ee[4];
  ee[0] = expf(l0 - mx); ee[1] = expf(l1 - mx); ee[2] = expf(l2 - mx); ee[3] = expf(l3 - mx);
  const float inv = 1.0f / (ee[0] + ee[1] + ee[2] + ee[3]);

  unsigned int* m = meta + (size_t)g * 20;
#pragma unroll
  for (int p = 0; p < PP; ++p) {
    const float a = ee[p] * inv;
    const float ox = oarow[h * 8 + p * 2 + 0];
    const float oy = oarow[h * 8 + p * 2 + 1];
    const float x = (rx + ox * (1.0f / HWc)) * (float)HWc - 0.5f;
    const float y = (ry + oy * (1.0f / HWc)) * (float)HWc - 0.5f;
    const float x0f = floorf(x), y0f = floorf(y);
    const int x0 = (int)x0f, y0 = (int)y0f;
    const float wx1 = x - x0f, wx0 = 1.f - wx1;
    const float wy1 = y - y0f, wy0 = 1.f - wy1;
    const bool vx0 = (unsigned)x0 < (unsigned)HWc, vx1 = (unsigned)(x0 + 1) < (unsigned)HWc;
    const bool vy0 = (unsigned)y0 < (unsigned)HWc, vy1 = (unsigned)(y0 + 1) < (unsigned)HWc;
    const int xi0 = min(max(x0, 0), HWc - 1), xi1 = min(max(x0 + 1, 0), HWc - 1);
    const int yi0 = min(max(y0, 0), HWc - 1), yi1 = min(max(y0 + 1, 0), HWc - 1);
    m[p] = (unsigned)xi0 | ((unsigned)yi0 << 8) | ((unsigned)xi1 << 16) | ((unsigned)yi1 << 24);
    float4 w;
    w.x = (vx0 && vy0) ? a * wx0 * wy0 : 0.f;
    w.y = (vx1 && vy0) ? a * wx1 * wy0 : 0.f;
    w.z = (vx0 && vy1) ? a * wx0 * wy1 : 0.f;
    w.w = (vx1 && vy1) ? a * wx1 * wy1 : 0.f;
    *(float4*)&m[4 + p * 4] = w;
  }
}

// ---------- gather + weighted accumulate; bf16 output ----------
__global__ __launch_bounds__(256) void sample_kernel(
    const float* __restrict__ vbuf,          // (B,HN,NV,DH) f32
    const unsigned int* __restrict__ meta,
    unsigned short* __restrict__ outs) {     // (B*NQ, 256) bf16
  const int t = threadIdx.x;
  const int d = t & 31;
  const int ql = t >> 5;
  const int sl = blockIdx.x >> 10;  // b*8+h
  const int qc = blockIdx.x & 1023;
  const int b = sl >> 3;
  const int h = sl & 7;
  const int q = qc * 8 + ql;
  const size_t bq = (size_t)b * NQc + q;
  const unsigned int* m = meta + ((size_t)bq * 8 + h) * 20;
  const uint4 pk = *(const uint4*)m;
  const float* vb = vbuf + (size_t)sl * (NVc * DH) + d;

  float acc = 0.f;
#pragma unroll
  for (int p = 0; p < PP; ++p) {
    const unsigned P = (p == 0) ? pk.x : (p == 1) ? pk.y : (p == 2) ? pk.z : pk.w;
    const float4 w = *(const float4*)(m + 4 + p * 4);
    const int x0 = P & 255, y0 = (P >> 8) & 255, x1 = (P >> 16) & 255, y1 = P >> 24;
    const int r0 = y0 << 12, r1 = y1 << 12;
    acc += w.x * vb[r0 + (x0 << 5)];
    acc += w.y * vb[r0 + (x1 << 5)];
    acc += w.z * vb[r1 + (x0 << 5)];
    acc += w.w * vb[r1 + (x1 << 5)];
  }
  outs[bq * EE + h * DH + d] = f2bf(acc);
}

extern "C" void kernel_launch(void* const* d_in, const int* in_sizes, int n_in,
                              void* d_out, int out_size, void* d_ws, size_t ws_size,
                              hipStream_t stream) {
  const float* query = (const float*)d_in[0];
  const float* value = (const float*)d_in[1];
  const float* ref2d = (const float*)d_in[2];
  const float* Woff  = (const float*)d_in[4];
  const float* boff  = (const float*)d_in[5];
  const float* Wattn = (const float*)d_in[6];
  const float* battn = (const float*)d_in[7];
  const float* Wval  = (const float*)d_in[8];
  const float* bval  = (const float*)d_in[9];
  const float* Wout  = (const float*)d_in[10];
  const float* bout  = (const float*)d_in[11];
  float* out = (float*)d_out;
  float* ws = (float*)d_ws;

  float* vbuf = ws;                               // 33,554,432 f (134 MB)
  float* oa_s = vbuf + 33554432;                  // 8,388,608 f (33.5 MB): oabuf f32, then sbuf bf16
  unsigned int* meta = (unsigned int*)(oa_s + 8388608);  // 10,485,760 u (42 MB)
  unsigned short* wvt = (unsigned short*)(meta + 10485760);  // 65536
  unsigned short* wot = wvt + 65536;                         // 65536
  unsigned short* wct = wot + 65536;                         // 32768
  float* bcat = (float*)(wct + 32768);                       // 128

  wprep<<<641, 256, 0, stream>>>(Wval, Wout, Woff, Wattn, boff, battn, wvt, wot, wct, bcat);

  mfma_gemm<MODE_VAL, false><<<dim3(1024, 2), 256, 0, stream>>>(
      (const void*)value, wvt, bval, nullptr, vbuf, 256);

  mfma_gemm<MODE_PLAIN, false><<<dim3(512, 1), 256, 0, stream>>>(
      (const void*)query, wct, bcat, nullptr, oa_s, 128);

  prep_points<<<2048, 256, 0, stream>>>(oa_s, ref2d, meta);

  sample_kernel<<<65536, 256, 0, stream>>>(vbuf, meta, (unsigned short*)oa_s);

  mfma_gemm<MODE_OUT, true><<<dim3(512, 2), 256, 0, stream>>>(
      (const void*)oa_s, wot, bout, query, out, 256);
}

// Round 3
// 439.691 us; speedup vs baseline: 1.9146x; 1.1561x over previous
//
#include <hip/hip_runtime.h>

typedef short s16x8 __attribute__((ext_vector_type(8)));
typedef float f32x4 __attribute__((ext_vector_type(4)));

#define HN 8
#define PP 4
#define DH 32
#define NQc 8192
#define NVc 16384
#define EE 256
#define HWc 128

__device__ __forceinline__ unsigned short f2bf(float x) {
  unsigned u = __float_as_uint(x);
  u += 0x7FFF + ((u >> 16) & 1);  // RNE
  return (unsigned short)(u >> 16);
}
__device__ __forceinline__ float bf2f(unsigned short h) {
  return __uint_as_float(((unsigned)h) << 16);
}

// ---------- weight prep: transpose+convert to bf16 [N][K], build bcat ----------
__global__ __launch_bounds__(256) void wprep(
    const float* __restrict__ Wval, const float* __restrict__ Wout,
    const float* __restrict__ Woff, const float* __restrict__ Wattn,
    const float* __restrict__ boff, const float* __restrict__ battn,
    unsigned short* __restrict__ wvt, unsigned short* __restrict__ wot,
    unsigned short* __restrict__ wct, float* __restrict__ bcat) {
  int g = blockIdx.x * 256 + threadIdx.x;
  if (g < 65536) {
    int n = g >> 8, k = g & 255;
    wvt[n * 256 + k] = f2bf(Wval[k * 256 + n]);
  } else if (g < 131072) {
    int g2 = g - 65536;
    int n = g2 >> 8, k = g2 & 255;
    wot[n * 256 + k] = f2bf(Wout[k * 256 + n]);
  } else if (g < 163840) {
    int g2 = g - 131072;
    int n = g2 >> 8, k = g2 & 255;
    float v = 0.f;
    if (n < 64) v = Woff[k * 64 + n];
    else if (n < 96) v = Wattn[k * 32 + (n - 64)];
    wct[n * 256 + k] = f2bf(v);
  } else if (g < 163968) {
    int c = g - 163840;
    bcat[c] = (c < 64) ? boff[c] : ((c < 96) ? battn[c - 64] : 0.f);
  }
}

// ---------- bf16 MFMA GEMM, BM=BN=128, BK=32, 4 waves x (4x4) 16x16x32 tiles ----------
#define MODE_VAL 0    // epilogue: bf16 + LDS transpose -> (B,HN,NV,DH) coalesced
#define MODE_PLAIN 1  // epilogue: fused softmax/loc prep -> meta
#define MODE_OUT 2    // epilogue: +bias +residual, coalesced f32 store

template <int MODE>
struct SmemBytes { static constexpr int v = 36864; };           // MODE_VAL: 128x144 bf16
template <> struct SmemBytes<MODE_PLAIN> { static constexpr int v = 49664; };  // 128x97 f32
template <> struct SmemBytes<MODE_OUT>   { static constexpr int v = 33792; };  // 64x132 f32

template <int MODE, bool ABF16>
__global__ __launch_bounds__(256) void mfma_gemm(
    const void* __restrict__ Ain, const unsigned short* __restrict__ Wt,
    const float* __restrict__ bias, const float* __restrict__ resid,
    const float* __restrict__ ref2d, unsigned int* __restrict__ meta,
    void* __restrict__ outp) {
  __shared__ __align__(16) char smem[SmemBytes<MODE>::v];
  unsigned short* As = (unsigned short*)smem;            // 128 x 40 shorts
  unsigned short* Ws = As + 128 * 40;                    // 128 x 40 shorts
  const int t = threadIdx.x;
  const int lane = t & 63, wave = t >> 6;
  const int lane15 = lane & 15, quad = lane >> 4;
  const int wr = wave >> 1, wc = wave & 1;
  const int bm = blockIdx.x * 128, bn = blockIdx.y * 128;

  f32x4 acc[4][4];
#pragma unroll
  for (int i = 0; i < 4; ++i)
#pragma unroll
    for (int j = 0; j < 4; ++j)
#pragma unroll
      for (int r = 0; r < 4; ++r) acc[i][j][r] = 0.f;

  const int ar = t >> 3, ac = (t & 7) * 4;   // f32 A staging
  const int wr2 = t >> 1, wcp = (t & 1) * 2; // bf16 chunk-pair staging

  for (int k0 = 0; k0 < 256; k0 += 32) {
    float4 av[4];
    uint4 ab0, ab1;
    if (!ABF16) {
      const float* Af = (const float*)Ain;
#pragma unroll
      for (int i = 0; i < 4; ++i)
        av[i] = *(const float4*)(Af + (size_t)(bm + ar + i * 32) * 256 + k0 + ac);
    } else {
      const unsigned short* Ab = (const unsigned short*)Ain;
      ab0 = *(const uint4*)(Ab + (size_t)(bm + wr2) * 256 + k0 + wcp * 8);
      ab1 = *(const uint4*)(Ab + (size_t)(bm + wr2) * 256 + k0 + wcp * 8 + 8);
    }
    uint4 wv0 = *(const uint4*)(Wt + (size_t)(bn + wr2) * 256 + k0 + wcp * 8);
    uint4 wv1 = *(const uint4*)(Wt + (size_t)(bn + wr2) * 256 + k0 + wcp * 8 + 8);
    __syncthreads();
    if (!ABF16) {
#pragma unroll
      for (int i = 0; i < 4; ++i) {
        ushort4 c;
        c.x = f2bf(av[i].x); c.y = f2bf(av[i].y); c.z = f2bf(av[i].z); c.w = f2bf(av[i].w);
        *(ushort4*)&As[(ar + i * 32) * 40 + ac] = c;
      }
    } else {
      *(uint4*)&As[wr2 * 40 + wcp * 8] = ab0;
      *(uint4*)&As[wr2 * 40 + wcp * 8 + 8] = ab1;
    }
    *(uint4*)&Ws[wr2 * 40 + wcp * 8] = wv0;
    *(uint4*)&Ws[wr2 * 40 + wcp * 8 + 8] = wv1;
    __syncthreads();
    s16x8 af[4], bfr[4];
#pragma unroll
    for (int tm = 0; tm < 4; ++tm)
      af[tm] = *(const s16x8*)&As[(wr * 64 + tm * 16 + lane15) * 40 + quad * 8];
#pragma unroll
    for (int tn = 0; tn < 4; ++tn)
      bfr[tn] = *(const s16x8*)&Ws[(wc * 64 + tn * 16 + lane15) * 40 + quad * 8];
#pragma unroll
    for (int tm = 0; tm < 4; ++tm)
#pragma unroll
      for (int tn = 0; tn < 4; ++tn)
        acc[tm][tn] = __builtin_amdgcn_mfma_f32_16x16x32_bf16(af[tm], bfr[tn], acc[tm][tn], 0, 0, 0);
  }

  if (MODE == MODE_VAL) {
    // ---- bf16 transpose through LDS, coalesced store to (B,HN,NV,DH) ----
    unsigned short* Ct = (unsigned short*)smem;  // 128 x 144
    __syncthreads();
#pragma unroll
    for (int tm = 0; tm < 4; ++tm)
#pragma unroll
      for (int tn = 0; tn < 4; ++tn) {
        const int coll = wc * 64 + tn * 16 + lane15;
        const float bcol = bias[bn + coll];
#pragma unroll
        for (int r = 0; r < 4; ++r) {
          const int rowl = wr * 64 + tm * 16 + quad * 4 + r;
          Ct[rowl * 144 + coll] = f2bf(acc[tm][tn][r] + bcol);
        }
      }
    __syncthreads();
    unsigned short* outs = (unsigned short*)outp;
    const int b = bm >> 14, n0 = bm & (NVc - 1), hbase = bn >> 5;
#pragma unroll
    for (int i = 0; i < 8; ++i) {
      const int id = i * 256 + t;
      const int h4 = id >> 9, rem = id & 511, n = rem >> 2, c4 = rem & 3;
      uint4 v = *(const uint4*)&Ct[n * 144 + h4 * 32 + c4 * 8];
      *(uint4*)(outs + (((size_t)(b * HN + hbase + h4) * NVc + n0 + n) * DH + c4 * 8)) = v;
    }
  } else if (MODE == MODE_PLAIN) {
    // ---- fused softmax + sampling-location prep -> meta ----
    float* Cf = (float*)smem;  // 128 x 97
    __syncthreads();
#pragma unroll
    for (int tm = 0; tm < 4; ++tm)
#pragma unroll
      for (int tn = 0; tn < 4; ++tn) {
        const int coll = wc * 64 + tn * 16 + lane15;
        if (coll < 96) {
          const float bcol = bias[coll];
#pragma unroll
          for (int r = 0; r < 4; ++r) {
            const int rowl = wr * 64 + tm * 16 + quad * 4 + r;
            Cf[rowl * 97 + coll] = acc[tm][tn][r] + bcol;
          }
        }
      }
    __syncthreads();
#pragma unroll
    for (int i = 0; i < 4; ++i) {
      const int task = i * 256 + t;
      const int h = task & 7, rowl = task >> 3;
      const int bq = bm + rowl;
      const float* row = Cf + rowl * 97;
      const float rx = ref2d[(size_t)bq * 2 + 0];
      const float ry = ref2d[(size_t)bq * 2 + 1];
      const float l0 = row[64 + h * 4 + 0], l1 = row[64 + h * 4 + 1];
      const float l2 = row[64 + h * 4 + 2], l3 = row[64 + h * 4 + 3];
      const float mx = fmaxf(fmaxf(l0, l1), fmaxf(l2, l3));
      float e0 = __expf(l0 - mx), e1 = __expf(l1 - mx), e2 = __expf(l2 - mx), e3 = __expf(l3 - mx);
      const float inv = 1.0f / (e0 + e1 + e2 + e3);
      float ee[4] = {e0, e1, e2, e3};
      unsigned int* m = meta + ((size_t)bq * 8 + h) * 20;
      uint4 pk;
      float4 wts[4];
#pragma unroll
      for (int p = 0; p < PP; ++p) {
        const float a = ee[p] * inv;
        const float ox = row[h * 8 + p * 2 + 0];
        const float oy = row[h * 8 + p * 2 + 1];
        const float x = (rx + ox * (1.0f / HWc)) * (float)HWc - 0.5f;
        const float y = (ry + oy * (1.0f / HWc)) * (float)HWc - 0.5f;
        const float x0f = floorf(x), y0f = floorf(y);
        const int x0 = (int)x0f, y0 = (int)y0f;
        const float wx1 = x - x0f, wx0 = 1.f - wx1;
        const float wy1 = y - y0f, wy0 = 1.f - wy1;
        const bool vx0 = (unsigned)x0 < (unsigned)HWc, vx1 = (unsigned)(x0 + 1) < (unsigned)HWc;
        const bool vy0 = (unsigned)y0 < (unsigned)HWc, vy1 = (unsigned)(y0 + 1) < (unsigned)HWc;
        const int xi0 = min(max(x0, 0), HWc - 1), xi1 = min(max(x0 + 1, 0), HWc - 1);
        const int yi0 = min(max(y0, 0), HWc - 1), yi1 = min(max(y0 + 1, 0), HWc - 1);
        const unsigned pv = (unsigned)xi0 | ((unsigned)yi0 << 8) | ((unsigned)xi1 << 16) | ((unsigned)yi1 << 24);
        if (p == 0) pk.x = pv; else if (p == 1) pk.y = pv; else if (p == 2) pk.z = pv; else pk.w = pv;
        float4 w;
        w.x = (vx0 && vy0) ? a * wx0 * wy0 : 0.f;
        w.y = (vx1 && vy0) ? a * wx1 * wy0 : 0.f;
        w.z = (vx0 && vy1) ? a * wx0 * wy1 : 0.f;
        w.w = (vx1 && vy1) ? a * wx1 * wy1 : 0.f;
        wts[p] = w;
      }
      *(uint4*)m = pk;
#pragma unroll
      for (int p = 0; p < PP; ++p) *(float4*)&m[4 + p * 4] = wts[p];
    }
  } else {
    // ---- MODE_OUT: two-pass f32 transpose, +resid, coalesced float4 store ----
    float* Cf = (float*)smem;  // 64 x 132
    float* outf = (float*)outp;
#pragma unroll
    for (int pass = 0; pass < 2; ++pass) {
      __syncthreads();
      if (wr == pass) {
#pragma unroll
        for (int tm = 0; tm < 4; ++tm)
#pragma unroll
          for (int tn = 0; tn < 4; ++tn) {
            const int coll = wc * 64 + tn * 16 + lane15;
            const float bcol = bias[bn + coll];
#pragma unroll
            for (int r = 0; r < 4; ++r) {
              const int rowl = tm * 16 + quad * 4 + r;
              Cf[rowl * 132 + coll] = acc[tm][tn][r] + bcol;
            }
          }
      }
      __syncthreads();
#pragma unroll
      for (int i = 0; i < 8; ++i) {
        const int id = i * 256 + t;
        const int n = id >> 5, c = id & 31;
        const size_t row = (size_t)bm + pass * 64 + n;
        float4 v = *(const float4*)&Cf[n * 132 + c * 4];
        float4 rs = *(const float4*)(resid + row * 256 + bn + c * 4);
        v.x += rs.x; v.y += rs.y; v.z += rs.z; v.w += rs.w;
        *(float4*)(outf + row * 256 + bn + c * 4) = v;
      }
    }
  }
}

// ---------- gather (bf16 vbuf) + weighted accumulate; bf16 output ----------
__global__ __launch_bounds__(256) void sample_kernel(
    const unsigned short* __restrict__ vbuf,  // (B,HN,NV,DH) bf16
    const unsigned int* __restrict__ meta,
    unsigned short* __restrict__ outs) {      // (B*NQ, 256) bf16
  const int t = threadIdx.x;
  const int d = t & 31;
  const int ql = t >> 5;
  const int sl = blockIdx.x >> 10;  // b*8+h
  const int qc = blockIdx.x & 1023;
  const int b = sl >> 3;
  const int h = sl & 7;
  const int q = qc * 8 + ql;
  const size_t bq = (size_t)b * NQc + q;
  const unsigned int* m = meta + ((size_t)bq * 8 + h) * 20;
  const uint4 pk = *(const uint4*)m;
  const unsigned short* vb = vbuf + (size_t)sl * (NVc * DH) + d;

  float acc = 0.f;
#pragma unroll
  for (int p = 0; p < PP; ++p) {
    const unsigned P = (p == 0) ? pk.x : (p == 1) ? pk.y : (p == 2) ? pk.z : pk.w;
    const float4 w = *(const float4*)(m + 4 + p * 4);
    const int x0 = P & 255, y0 = (P >> 8) & 255, x1 = (P >> 16) & 255, y1 = P >> 24;
    const int r0 = y0 << 12, r1 = y1 << 12;
    acc += w.x * bf2f(vb[r0 + (x0 << 5)]);
    acc += w.y * bf2f(vb[r0 + (x1 << 5)]);
    acc += w.z * bf2f(vb[r1 + (x0 << 5)]);
    acc += w.w * bf2f(vb[r1 + (x1 << 5)]);
  }
  outs[bq * EE + h * DH + d] = f2bf(acc);
}

extern "C" void kernel_launch(void* const* d_in, const int* in_sizes, int n_in,
                              void* d_out, int out_size, void* d_ws, size_t ws_size,
                              hipStream_t stream) {
  const float* query = (const float*)d_in[0];
  const float* value = (const float*)d_in[1];
  const float* ref2d = (const float*)d_in[2];
  const float* Woff  = (const float*)d_in[4];
  const float* boff  = (const float*)d_in[5];
  const float* Wattn = (const float*)d_in[6];
  const float* battn = (const float*)d_in[7];
  const float* Wval  = (const float*)d_in[8];
  const float* bval  = (const float*)d_in[9];
  const float* Wout  = (const float*)d_in[10];
  const float* bout  = (const float*)d_in[11];
  float* out = (float*)d_out;

  unsigned short* vbuf = (unsigned short*)d_ws;                 // 33,554,432 us (64 MB)
  unsigned int* meta   = (unsigned int*)(vbuf + 33554432);      // 10,485,760 u (40 MB)
  unsigned short* sbuf = (unsigned short*)(meta + 10485760);    // 16,777,216 us (32 MB)
  unsigned short* wvt  = sbuf + 16777216;                       // 65536
  unsigned short* wot  = wvt + 65536;                           // 65536
  unsigned short* wct  = wot + 65536;                           // 32768
  float* bcat          = (float*)(wct + 32768);                 // 128

  wprep<<<641, 256, 0, stream>>>(Wval, Wout, Woff, Wattn, boff, battn, wvt, wot, wct, bcat);

  mfma_gemm<MODE_VAL, false><<<dim3(1024, 2), 256, 0, stream>>>(
      (const void*)value, wvt, bval, nullptr, nullptr, nullptr, (void*)vbuf);

  mfma_gemm<MODE_PLAIN, false><<<dim3(512, 1), 256, 0, stream>>>(
      (const void*)query, wct, bcat, nullptr, ref2d, meta, nullptr);

  sample_kernel<<<65536, 256, 0, stream>>>(vbuf, meta, sbuf);

  mfma_gemm<MODE_OUT, true><<<dim3(512, 2), 256, 0, stream>>>(
      (const void*)sbuf, wot, bout, query, nullptr, nullptr, (void*)out);
}